// Round 18
// baseline (157.709 us; speedup 1.0000x reference)
//
#include <hip/hip_runtime.h>
#include <hip/hip_bf16.h>
#include <cstdint>
#include <cstddef>

// Problem dims
#define Bb 2
#define Tt 2048
#define Dd 1024
#define Hh 16
#define DHh 64

using short8 = __attribute__((ext_vector_type(8))) short;   // 8 bf16 (4 VGPRs) MFMA operand
using f32x4  = __attribute__((ext_vector_type(4))) float;   // MFMA accumulator 16x16
typedef unsigned short u16;

// f32 -> bf16 (RNE) scalar
__device__ __forceinline__ u16 f2bf(float f) {
    unsigned int u = __float_as_uint(f);
    u += 0x7fffu + ((u >> 16) & 1u);
    return (u16)(u >> 16);
}

// pack two f32 -> bf16x2 (v_cvt_pk_bf16_f32 via HIP API)
__device__ __forceinline__ unsigned int pk2bf(float a, float b) {
    union { __hip_bfloat162 h; unsigned int u; } c;
    c.h = __float22bfloat162_rn(float2{a, b});
    return c.u;
}

// async global->LDS, 16B per lane; LDS dest is wave-uniform base + lane*16
__device__ __forceinline__ void gload16(const void* g, void* l) {
    __builtin_amdgcn_global_load_lds((const __attribute__((address_space(1))) void*)g,
                                     (__attribute__((address_space(3))) void*)l, 16, 0, 0);
}

// ---------------------------------------------------------------------------
// m97-style GEMM core: C[128x128] of A[M,K] @ BT[N,K]^T, bf16 in, f32 acc.
// BK=32, 16KB LDS (measured best for qkv among 5 variants).
// ---------------------------------------------------------------------------
__device__ __forceinline__ void gemm_bt_core(const u16* __restrict__ A, const u16* __restrict__ BT,
                                             int K, int m0, int n0,
                                             u16* As, u16* Bs, f32x4 acc[4][4]) {
    const int tid = threadIdx.x;
    const int w = tid >> 6, lane = tid & 63;
    const int lr = lane & 15, lg = lane >> 4;
    const int wr = w >> 1, wc = w & 1;
    const int arow = lane >> 2;
    const int acol = (lane & 3) * 8;
    for (int kk = 0; kk < K; kk += 32) {
        __syncthreads();
#pragma unroll
        for (int j = 0; j < 2; ++j) {
            int r0 = w * 32 + j * 16;
            gload16(A  + (size_t)(m0 + r0 + arow) * K + kk + acol, (char*)As + r0 * 64);
            gload16(BT + (size_t)(n0 + r0 + arow) * K + kk + acol, (char*)Bs + r0 * 64);
        }
        __syncthreads();
        short8 af[4], bfv[4];
#pragma unroll
        for (int m = 0; m < 4; ++m)
            af[m] = *(const short8*)((const char*)As + ((wr * 64 + m * 16 + lr) * 64 + lg * 16));
#pragma unroll
        for (int n = 0; n < 4; ++n)
            bfv[n] = *(const short8*)((const char*)Bs + ((wc * 64 + n * 16 + lr) * 64 + lg * 16));
#pragma unroll
        for (int m = 0; m < 4; ++m)
#pragma unroll
            for (int n = 0; n < 4; ++n)
                acc[m][n] = __builtin_amdgcn_mfma_f32_16x16x32_bf16(af[m], bfv[n], acc[m][n], 0, 0, 0);
    }
}

// ---------------------------------------------------------------------------
// Fused prep (one launch): grid.y==0 -> x f32->bf16 + dmask->f32 bias;
// grid.y==1 -> W[k][n] f32 -> WT[n][k] bf16 for Wq,Wk,Wv,Wp.
// ---------------------------------------------------------------------------
__global__ __launch_bounds__(256) void prep_k(const float4* __restrict__ x4,
                                              ushort4* __restrict__ xb4, int n4,
                                              const int* __restrict__ dmask,
                                              float* __restrict__ dmb,
                                              const float* __restrict__ Wq, const float* __restrict__ Wk,
                                              const float* __restrict__ Wv, const float* __restrict__ Wp,
                                              u16* __restrict__ wt) {
    const int tid = threadIdx.x;
    if (blockIdx.y == 0) {
        int i = blockIdx.x * 256 + tid;
        if (i < n4) {
            float4 v = x4[i];
            ushort4 o;
            o.x = f2bf(v.x); o.y = f2bf(v.y); o.z = f2bf(v.z); o.w = f2bf(v.w);
            xb4[i] = o;
        }
        if (i < Bb * Tt) dmb[i] = dmask[i] ? 0.f : -15000.f;
    } else {
        __shared__ float tile[32][33];
        const int bid = (int)blockIdx.x;          // 0..4095 = 4 x 32 x 32
        const int z = bid >> 10, rem = bid & 1023;
        const int n0 = (rem & 31) * 32, k0 = (rem >> 5) * 32;
        const float* W = (z == 0) ? Wq : (z == 1) ? Wk : (z == 2) ? Wv : Wp;
        const int tx = tid & 31, ty = tid >> 5;   // (32, 8)
#pragma unroll
        for (int j = 0; j < 4; ++j)
            tile[ty + j * 8][tx] = W[(size_t)(k0 + ty + j * 8) * Dd + n0 + tx];
        __syncthreads();
        u16* outp = wt + (size_t)z * Dd * Dd;
#pragma unroll
        for (int j = 0; j < 4; ++j)
            outp[(size_t)(n0 + ty + j * 8) * Dd + k0 + tx] = f2bf(tile[tx][ty + j * 8]);
    }
}

// ---------------------------------------------------------------------------
// QKV GEMM (R14-exact: m97 128^2 BK=32 + T1 XCD swizzle, 768 blocks = 8x96).
// Epilogue: Q scaled (incl log2e), K per-head, V PRE-PERMUTED+PRE-SWIZZLED
// in 128-key 16KB tiles: VTg[bh][kt][dh][128pos]
//   a = t&127; pos = 32*(a>>5) + ((a&15)>>2)*8 + ((a>>4)&1)*4 + (a&3)  (PV pi)
//   chunk' = (pos>>3) ^ (dh&7)                                          (bank swz)
// ---------------------------------------------------------------------------
__global__ __launch_bounds__(256) void qkv_gemm_k(const u16* __restrict__ xb, const u16* __restrict__ wt,
        const float* __restrict__ bq, const float* __restrict__ bk, const float* __restrict__ bv,
        u16* __restrict__ Qg, u16* __restrict__ Kg, u16* __restrict__ VTg) {
    __shared__ alignas(16) u16 As[128 * 32];
    __shared__ alignas(16) u16 Bs[128 * 32];
    f32x4 acc[4][4];
    const f32x4 vzero = {0.f, 0.f, 0.f, 0.f};
#pragma unroll
    for (int m = 0; m < 4; ++m)
#pragma unroll
        for (int n = 0; n < 4; ++n) acc[m][n] = vzero;
    // T1 XCD-bijective swizzle (768 = 8 XCDs x 96 blocks)
    const int lin = (int)blockIdx.x;
    const int swz = (lin & 7) * 96 + (lin >> 3);
    const int bx = swz % 24, by = swz / 24;
    const int m0 = by * 128, n0 = bx * 128;
    gemm_bt_core(xb, wt, 1024, m0, n0, As, Bs, acc);
    const int tid = threadIdx.x, w = tid >> 6, lane = tid & 63, lr = lane & 15, lg = lane >> 4;
    const int wr = w >> 1, wc = w & 1;
    const int sec = n0 >> 10;             // 0:Q 1:K 2:V (128-tiles never straddle)
    const float* bias = (sec == 0) ? bq : (sec == 1) ? bk : bv;
    u16* dst = (sec == 0) ? Qg : (sec == 1) ? Kg : VTg;
    // Q scale: DH^-0.5 * log2(e)  -> softmax runs in exp2 domain
    const float qscale = (sec == 0) ? 0.125f * 1.4426950408889634f : 1.0f;
#pragma unroll
    for (int n = 0; n < 4; ++n) {
        int gn = n0 + wc * 64 + n * 16 + lr;
        int j = gn & 1023;
        float bj = bias[j];
        int h = j >> 6, dh = j & 63;
#pragma unroll
        for (int m = 0; m < 4; ++m) {
            int gmb = m0 + wr * 64 + m * 16 + 4 * lg;
#pragma unroll
            for (int i = 0; i < 4; ++i) {
                int gm = gmb + i;
                int b = gm >> 11, t = gm & 2047;
                float v = (acc[m][n][i] + bj) * qscale;
                size_t off;
                if (sec < 2) off = (((size_t)(b * Hh + h)) * Tt + t) * DHh + dh;       // [bh][t][dh]
                else {
                    int kt2 = t >> 7, a = t & 127;
                    int ks2 = a >> 5, r = a & 31;
                    int pos = ks2 * 32 + ((r & 15) >> 2) * 8 + ((r >> 4) & 1) * 4 + (r & 3);
                    int chunkp = (pos >> 3) ^ (dh & 7);
                    off = (((size_t)(b * Hh + h) * 16 + kt2) * 64 + dh) * 128 + chunkp * 8 + (pos & 7);
                }
                dst[off] = f2bf(v);
            }
        }
    }
}

// ---------------------------------------------------------------------------
// Flash attention (R8 structure, K DIRECT FROM GLOBAL): swapped-operand
// 16x16, 4 waves x 16 q-rows, K-tile 128. K-fragments load straight from L2
// (coalesced: k0v+k1v jointly cover each 128B K-row) — no Ks LDS, no K
// staging; LDS halves to 16KB (V only) and the barrier guards only the
// 4-instr V stage. No-max softmax (exp2 domain); mask via QK C-operand bias;
// causal subtract on diagonal tiles; PV B-operand lane-local via pi-permuted
// VTg; l on the MFMA pipe.
// ---------------------------------------------------------------------------
__global__ __launch_bounds__(256, 4) void attn_k(const u16* __restrict__ Qg, const u16* __restrict__ Kg,
        const u16* __restrict__ VTg, const float* __restrict__ dmb, u16* __restrict__ Og) {
    __shared__ alignas(16) u16 Vs[64 * 128];     // [dh][pos] rows 256B, pre-swz in VTg (16KB)
    const int bh = blockIdx.x;
    const int qb = (int)gridDim.y - 1 - (int)blockIdx.y;  // heavy blocks first
    const int b = bh >> 4, h = bh & 15;
    const int tid = threadIdx.x, w = tid >> 6, lane = tid & 63;
    const int lr = lane & 15, lg = lane >> 4;
    const int q0 = qb * 64 + w * 16;
    const int qrow = q0 + lr;
    const u16* Qbase = Qg + ((size_t)bh * Tt + q0) * DHh;
    short8 qf0 = *(const short8*)(Qbase + lr * DHh + lg * 8);
    short8 qf1 = *(const short8*)(Qbase + lr * DHh + 32 + lg * 8);
    const f32x4 vzero = {0.f, 0.f, 0.f, 0.f};
    const short8 ones8 = {(short)0x3F80, (short)0x3F80, (short)0x3F80, (short)0x3F80,
                          (short)0x3F80, (short)0x3F80, (short)0x3F80, (short)0x3F80};
    f32x4 o[4];
#pragma unroll
    for (int n = 0; n < 4; ++n) o[n] = vzero;
    f32x4 acc_l = vzero;                          // l accumulates on MFMA pipe
    const int ktiles = (qb * 64 + 63) / 128 + 1;
    char* VsB = (char*)Vs;

    for (int kt = 0; kt < ktiles; ++kt) {
        const int kbase = kt * 128;
        __syncthreads();                          // prev tile's V reads done
        // stage V tile: LINEAR 4KB per wave from pre-permuted VTg
        {
            const u16* vsrc = VTg + (((size_t)bh * 16 + kt) * 8192) + w * 2048 + lane * 8;
#pragma unroll
            for (int j = 0; j < 4; ++j)
                gload16(vsrc + j * 512, VsB + w * 4096 + j * 1024);
        }
        __syncthreads();                          // V staged visible (drains vmcnt)
        // S^T = K Q^T + mask-bias (C-operand): lane q = lr, k = 16*nf + 4*lg + i
        // K fragments DIRECT from global (L2-resident, coalesced per row)
        f32x4 s[8];
        const float* bb = dmb + (size_t)b * Tt + kbase + 4 * lg;
        const u16* Kt = Kg + ((size_t)bh * Tt + kbase) * DHh;
#pragma unroll
        for (int nf = 0; nf < 8; ++nf) {
            int r = nf * 16 + lr;
            short8 k0v = *(const short8*)(Kt + r * DHh + lg * 8);
            short8 k1v = *(const short8*)(Kt + r * DHh + 32 + lg * 8);
            f32x4 cin = *(const f32x4*)(bb + nf * 16);
            f32x4 t0 = __builtin_amdgcn_mfma_f32_16x16x32_bf16(k0v, qf0, cin, 0, 0, 0);
            s[nf] = __builtin_amdgcn_mfma_f32_16x16x32_bf16(k1v, qf1, t0, 0, 0, 0);
        }
        // causal cut, diagonal tiles only (wave-uniform branch)
        if (kbase + 127 > q0) {
#pragma unroll
            for (int nf = 0; nf < 8; ++nf) {
                int tk = kbase + 16 * nf + 4 * lg;
#pragma unroll
                for (int i = 0; i < 4; ++i)
                    if (tk + i > qrow) s[nf][i] -= 15000.f;
            }
        }
        // PV: pf lane-local (pi-permuted keys), V read matches pi via VTg layout
#pragma unroll
        for (int ks = 0; ks < 4; ++ks) {
            union { uint4 u; short8 sv; } pf;
            pf.u.x = pk2bf(exp2f(s[2 * ks][0]), exp2f(s[2 * ks][1]));
            pf.u.y = pk2bf(exp2f(s[2 * ks][2]), exp2f(s[2 * ks][3]));
            pf.u.z = pk2bf(exp2f(s[2 * ks + 1][0]), exp2f(s[2 * ks + 1][1]));
            pf.u.w = pk2bf(exp2f(s[2 * ks + 1][2]), exp2f(s[2 * ks + 1][3]));
            acc_l = __builtin_amdgcn_mfma_f32_16x16x32_bf16(ones8, pf.sv, acc_l, 0, 0, 0);
#pragma unroll
            for (int n = 0; n < 4; ++n) {
                int rv = n * 16 + lr;
                short8 vf = *(const short8*)(VsB + rv * 256 + ((((ks * 4 + lg)) ^ (rv & 7)) << 4));
                o[n] = __builtin_amdgcn_mfma_f32_16x16x32_bf16(vf, pf.sv, o[n], 0, 0, 0);
            }
        }
    }
    // epilogue: normalize by l = acc_l[0] (same value across D rows), write O
    float l = acc_l[0];
    float inv = l > 0.f ? 1.0f / l : 0.f;
#pragma unroll
    for (int n = 0; n < 4; ++n) {
        uint2 pw;
        pw.x = pk2bf(o[n][0] * inv, o[n][1] * inv);
        pw.y = pk2bf(o[n][2] * inv, o[n][3] * inv);
        *(uint2*)(Og + ((size_t)(b * Tt + qrow)) * Dd + h * DHh + n * 16 + 4 * lg) = pw;
    }
}

// ---------------------------------------------------------------------------
// Output GEMM (R11-measured ~13.5us): 64x128 tiles, grid (8,64)=512 blocks,
// LDS 12KB -> high occupancy. 4 waves (2x2), each 32x64.
// ---------------------------------------------------------------------------
__global__ __launch_bounds__(256) void out_gemm_k(const u16* __restrict__ Og, const u16* __restrict__ wpt,
        const float* __restrict__ bp, const int* __restrict__ dmask, float* __restrict__ out) {
    __shared__ alignas(16) u16 As[64 * 32];    // 4KB
    __shared__ alignas(16) u16 Bs[128 * 32];   // 8KB
    f32x4 acc[2][4];
    const f32x4 vzero = {0.f, 0.f, 0.f, 0.f};
#pragma unroll
    for (int m = 0; m < 2; ++m)
#pragma unroll
        for (int n = 0; n < 4; ++n) acc[m][n] = vzero;
    const int m0 = blockIdx.y * 64, n0 = blockIdx.x * 128;
    const int tid = threadIdx.x, w = tid >> 6, lane = tid & 63, lr = lane & 15, lg = lane >> 4;
    const int wr = w >> 1, wc = w & 1;

    for (int kk = 0; kk < 1024; kk += 32) {
        __syncthreads();
        {
            int row = tid >> 2, c = tid & 3;    // A: 64 rows x 4 chunks
            gload16(Og + (size_t)(m0 + row) * 1024 + kk + c * 8, (char*)As + tid * 16);
#pragma unroll
            for (int j = 0; j < 2; ++j) {
                int idx = tid + j * 256;        // B: 128 rows x 4 chunks
                int rowb = idx >> 2, cb = idx & 3;
                gload16(wpt + (size_t)(n0 + rowb) * 1024 + kk + cb * 8, (char*)Bs + idx * 16);
            }
        }
        __syncthreads();
        short8 af[2], bf[4];
#pragma unroll
        for (int m = 0; m < 2; ++m) {
            int ra = wr * 32 + m * 16 + lr;
            af[m] = *(const short8*)((const char*)As + ra * 64 + lg * 16);
        }
#pragma unroll
        for (int n = 0; n < 4; ++n) {
            int rb = wc * 64 + n * 16 + lr;
            bf[n] = *(const short8*)((const char*)Bs + rb * 64 + lg * 16);
        }
#pragma unroll
        for (int m = 0; m < 2; ++m)
#pragma unroll
            for (int n = 0; n < 4; ++n)
                acc[m][n] = __builtin_amdgcn_mfma_f32_16x16x32_bf16(af[m], bf[n], acc[m][n], 0, 0, 0);
    }
#pragma unroll
    for (int n = 0; n < 4; ++n) {
        int gn = n0 + wc * 64 + n * 16 + lr;
        float bj = bp[gn];
#pragma unroll
        for (int m = 0; m < 2; ++m) {
            int gmb = m0 + wr * 32 + m * 16 + 4 * lg;
#pragma unroll
            for (int i = 0; i < 4; ++i) {
                int gm = gmb + i;
                float dmv = (float)dmask[gm];
                out[(size_t)gm * Dd + gn] = (acc[m][n][i] + bj) * dmv;
            }
        }
    }
}

// ---------------------------------------------------------------------------
// Workspace layout (bytes):
//   [0,8M)    xb  bf16 [4096][1024]   (reused as Og after qkv_gemm)
//   [8M,16M)  wt  bf16 [4][1024][1024] (WqT,WkT,WvT,WpT)
//   [16M,24M) Qg  bf16 [32][2048][64]  (scaled incl log2e)
//   [24M,32M) Kg  bf16 [32][2048][64]
//   [32M,40M) VTg bf16 [32][16][64][128] (V pre-permuted 128-key 16KB tiles)
//   [40M,+16K) dmb f32 [2][2048] additive mask bias
// ---------------------------------------------------------------------------
extern "C" void kernel_launch(void* const* d_in, const int* in_sizes, int n_in,
                              void* d_out, int out_size, void* d_ws, size_t ws_size,
                              hipStream_t stream) {
    const float* x   = (const float*)d_in[0];
    const int*  dmask = (const int*)d_in[1];
    const float* Wq = (const float*)d_in[2];
    const float* bq = (const float*)d_in[3];
    const float* Wk = (const float*)d_in[4];
    const float* bk = (const float*)d_in[5];
    const float* Wv = (const float*)d_in[6];
    const float* bv = (const float*)d_in[7];
    const float* Wp = (const float*)d_in[8];
    const float* bp = (const float*)d_in[9];
    float* out = (float*)d_out;
    char* ws = (char*)d_ws;
    u16* xb  = (u16*)(ws);
    u16* wt  = (u16*)(ws + ((size_t)8 << 20));
    u16* Qg  = (u16*)(ws + ((size_t)16 << 20));
    u16* Kg  = (u16*)(ws + ((size_t)24 << 20));
    u16* VTg = (u16*)(ws + ((size_t)32 << 20));
    float* dmb = (float*)(ws + ((size_t)40 << 20));
    u16* Og  = xb;   // reuse: xb consumed by qkv_gemm before attn writes Og

    prep_k<<<dim3(4096, 2), dim3(256), 0, stream>>>((const float4*)x, (ushort4*)xb,
                                                    (Bb * Tt * Dd) / 4, dmask, dmb,
                                                    Wq, Wk, Wv, Wp, wt);
    qkv_gemm_k<<<dim3(768), dim3(256), 0, stream>>>(xb, wt, bq, bk, bv, Qg, Kg, VTg);
    attn_k<<<dim3(32, 32), dim3(256), 0, stream>>>(Qg, Kg, VTg, dmb, Og);
    out_gemm_k<<<dim3(8, 64), dim3(256), 0, stream>>>(Og, wt + (size_t)3 * Dd * Dd, bp, dmask, out);
}

// Round 19
// 106.239 us; speedup vs baseline: 1.4845x; 1.4845x over previous
//
#include <hip/hip_runtime.h>
#include <hip/hip_bf16.h>
#include <cstdint>
#include <cstddef>

// Problem dims
#define Bb 2
#define Tt 2048
#define Dd 1024
#define Hh 16
#define DHh 64

using short8 = __attribute__((ext_vector_type(8))) short;   // 8 bf16 (4 VGPRs) MFMA operand
using f32x4  = __attribute__((ext_vector_type(4))) float;   // MFMA accumulator 16x16
typedef unsigned short u16;

// f32 -> bf16 (RNE) scalar
__device__ __forceinline__ u16 f2bf(float f) {
    unsigned int u = __float_as_uint(f);
    u += 0x7fffu + ((u >> 16) & 1u);
    return (u16)(u >> 16);
}

// pack two f32 -> bf16x2 (v_cvt_pk_bf16_f32 via HIP API)
__device__ __forceinline__ unsigned int pk2bf(float a, float b) {
    union { __hip_bfloat162 h; unsigned int u; } c;
    c.h = __float22bfloat162_rn(float2{a, b});
    return c.u;
}

// async global->LDS, 16B per lane; LDS dest is wave-uniform base + lane*16
__device__ __forceinline__ void gload16(const void* g, void* l) {
    __builtin_amdgcn_global_load_lds((const __attribute__((address_space(1))) void*)g,
                                     (__attribute__((address_space(3))) void*)l, 16, 0, 0);
}

// ---------------------------------------------------------------------------
// m97-style GEMM core: C[128x128] of A[M,K] @ BT[N,K]^T, bf16 in, f32 acc.
// BK=32, 16KB LDS (measured best for qkv among 5 variants).
// ---------------------------------------------------------------------------
__device__ __forceinline__ void gemm_bt_core(const u16* __restrict__ A, const u16* __restrict__ BT,
                                             int K, int m0, int n0,
                                             u16* As, u16* Bs, f32x4 acc[4][4]) {
    const int tid = threadIdx.x;
    const int w = tid >> 6, lane = tid & 63;
    const int lr = lane & 15, lg = lane >> 4;
    const int wr = w >> 1, wc = w & 1;
    const int arow = lane >> 2;
    const int acol = (lane & 3) * 8;
    for (int kk = 0; kk < K; kk += 32) {
        __syncthreads();
#pragma unroll
        for (int j = 0; j < 2; ++j) {
            int r0 = w * 32 + j * 16;
            gload16(A  + (size_t)(m0 + r0 + arow) * K + kk + acol, (char*)As + r0 * 64);
            gload16(BT + (size_t)(n0 + r0 + arow) * K + kk + acol, (char*)Bs + r0 * 64);
        }
        __syncthreads();
        short8 af[4], bfv[4];
#pragma unroll
        for (int m = 0; m < 4; ++m)
            af[m] = *(const short8*)((const char*)As + ((wr * 64 + m * 16 + lr) * 64 + lg * 16));
#pragma unroll
        for (int n = 0; n < 4; ++n)
            bfv[n] = *(const short8*)((const char*)Bs + ((wc * 64 + n * 16 + lr) * 64 + lg * 16));
#pragma unroll
        for (int m = 0; m < 4; ++m)
#pragma unroll
            for (int n = 0; n < 4; ++n)
                acc[m][n] = __builtin_amdgcn_mfma_f32_16x16x32_bf16(af[m], bfv[n], acc[m][n], 0, 0, 0);
    }
}

// ---------------------------------------------------------------------------
// Fused prep (one launch): grid.y==0 -> x f32->bf16 + dmask->f32 bias;
// grid.y==1 -> W[k][n] f32 -> WT[n][k] bf16 for Wq,Wk,Wv,Wp.
// ---------------------------------------------------------------------------
__global__ __launch_bounds__(256) void prep_k(const float4* __restrict__ x4,
                                              ushort4* __restrict__ xb4, int n4,
                                              const int* __restrict__ dmask,
                                              float* __restrict__ dmb,
                                              const float* __restrict__ Wq, const float* __restrict__ Wk,
                                              const float* __restrict__ Wv, const float* __restrict__ Wp,
                                              u16* __restrict__ wt) {
    const int tid = threadIdx.x;
    if (blockIdx.y == 0) {
        int i = blockIdx.x * 256 + tid;
        if (i < n4) {
            float4 v = x4[i];
            ushort4 o;
            o.x = f2bf(v.x); o.y = f2bf(v.y); o.z = f2bf(v.z); o.w = f2bf(v.w);
            xb4[i] = o;
        }
        if (i < Bb * Tt) dmb[i] = dmask[i] ? 0.f : -15000.f;
    } else {
        __shared__ float tile[32][33];
        const int bid = (int)blockIdx.x;          // 0..4095 = 4 x 32 x 32
        const int z = bid >> 10, rem = bid & 1023;
        const int n0 = (rem & 31) * 32, k0 = (rem >> 5) * 32;
        const float* W = (z == 0) ? Wq : (z == 1) ? Wk : (z == 2) ? Wv : Wp;
        const int tx = tid & 31, ty = tid >> 5;   // (32, 8)
#pragma unroll
        for (int j = 0; j < 4; ++j)
            tile[ty + j * 8][tx] = W[(size_t)(k0 + ty + j * 8) * Dd + n0 + tx];
        __syncthreads();
        u16* outp = wt + (size_t)z * Dd * Dd;
#pragma unroll
        for (int j = 0; j < 4; ++j)
            outp[(size_t)(n0 + ty + j * 8) * Dd + k0 + tx] = f2bf(tile[tx][ty + j * 8]);
    }
}

// ---------------------------------------------------------------------------
// QKV GEMM (m97 128^2 BK=32 + T1 XCD swizzle, 768 blocks = 8x96).
// Epilogue: Q scaled (incl log2e), K per-head, V PRE-PERMUTED+PRE-SWIZZLED
// in 128-key 16KB tiles: VTg[bh][kt][dh][128pos]
//   a = t&127; pos = 32*(a>>5) + ((a&15)>>2)*8 + ((a>>4)&1)*4 + (a&3)  (PV pi)
//   chunk' = (pos>>3) ^ (dh&7)                                          (bank swz)
// ---------------------------------------------------------------------------
__global__ __launch_bounds__(256) void qkv_gemm_k(const u16* __restrict__ xb, const u16* __restrict__ wt,
        const float* __restrict__ bq, const float* __restrict__ bk, const float* __restrict__ bv,
        u16* __restrict__ Qg, u16* __restrict__ Kg, u16* __restrict__ VTg) {
    __shared__ alignas(16) u16 As[128 * 32];
    __shared__ alignas(16) u16 Bs[128 * 32];
    f32x4 acc[4][4];
    const f32x4 vzero = {0.f, 0.f, 0.f, 0.f};
#pragma unroll
    for (int m = 0; m < 4; ++m)
#pragma unroll
        for (int n = 0; n < 4; ++n) acc[m][n] = vzero;
    // T1 XCD-bijective swizzle (768 = 8 XCDs x 96 blocks)
    const int lin = (int)blockIdx.x;
    const int swz = (lin & 7) * 96 + (lin >> 3);
    const int bx = swz % 24, by = swz / 24;
    const int m0 = by * 128, n0 = bx * 128;
    gemm_bt_core(xb, wt, 1024, m0, n0, As, Bs, acc);
    const int tid = threadIdx.x, w = tid >> 6, lane = tid & 63, lr = lane & 15, lg = lane >> 4;
    const int wr = w >> 1, wc = w & 1;
    const int sec = n0 >> 10;             // 0:Q 1:K 2:V (128-tiles never straddle)
    const float* bias = (sec == 0) ? bq : (sec == 1) ? bk : bv;
    u16* dst = (sec == 0) ? Qg : (sec == 1) ? Kg : VTg;
    // Q scale: DH^-0.5 * log2(e)  -> softmax runs in exp2 domain
    const float qscale = (sec == 0) ? 0.125f * 1.4426950408889634f : 1.0f;
#pragma unroll
    for (int n = 0; n < 4; ++n) {
        int gn = n0 + wc * 64 + n * 16 + lr;
        int j = gn & 1023;
        float bj = bias[j];
        int h = j >> 6, dh = j & 63;
#pragma unroll
        for (int m = 0; m < 4; ++m) {
            int gmb = m0 + wr * 64 + m * 16 + 4 * lg;
#pragma unroll
            for (int i = 0; i < 4; ++i) {
                int gm = gmb + i;
                int b = gm >> 11, t = gm & 2047;
                float v = (acc[m][n][i] + bj) * qscale;
                size_t off;
                if (sec < 2) off = (((size_t)(b * Hh + h)) * Tt + t) * DHh + dh;       // [bh][t][dh]
                else {
                    int kt2 = t >> 7, a = t & 127;
                    int ks2 = a >> 5, r = a & 31;
                    int pos = ks2 * 32 + ((r & 15) >> 2) * 8 + ((r >> 4) & 1) * 4 + (r & 3);
                    int chunkp = (pos >> 3) ^ (dh & 7);
                    off = (((size_t)(b * Hh + h) * 16 + kt2) * 64 + dh) * 128 + chunkp * 8 + (pos & 7);
                }
                dst[off] = f2bf(v);
            }
        }
    }
}

// ---------------------------------------------------------------------------
// Flash attention (R8-exact, the measured optimum of 9 structure variants):
// swapped-operand 16x16, 4 waves x 16 q-rows, K-tile 128, single-buffered
// 32KB LDS. No-max softmax (exp2 domain). Mask via QK C-operand bias
// (0/-15000); causal subtract on diagonal tiles. PV B-operand lane-local via
// pi-permuted VTg (no P LDS). l on the MFMA pipe via ones x P.
// ---------------------------------------------------------------------------
__global__ __launch_bounds__(256, 4) void attn_k(const u16* __restrict__ Qg, const u16* __restrict__ Kg,
        const u16* __restrict__ VTg, const float* __restrict__ dmb, u16* __restrict__ Og) {
    __shared__ alignas(16) u16 Ks[128 * 64];     // [key][dh]   rows 128B, chunk-swz
    __shared__ alignas(16) u16 Vs[64 * 128];     // [dh][pos]   rows 256B, pre-swz in VTg
    const int bh = blockIdx.x;
    const int qb = (int)gridDim.y - 1 - (int)blockIdx.y;  // heavy blocks first
    const int b = bh >> 4, h = bh & 15;
    const int tid = threadIdx.x, w = tid >> 6, lane = tid & 63;
    const int lr = lane & 15, lg = lane >> 4;
    const int q0 = qb * 64 + w * 16;
    const int qrow = q0 + lr;
    const u16* Qbase = Qg + ((size_t)bh * Tt + q0) * DHh;
    short8 qf0 = *(const short8*)(Qbase + lr * DHh + lg * 8);
    short8 qf1 = *(const short8*)(Qbase + lr * DHh + 32 + lg * 8);
    const f32x4 vzero = {0.f, 0.f, 0.f, 0.f};
    const short8 ones8 = {(short)0x3F80, (short)0x3F80, (short)0x3F80, (short)0x3F80,
                          (short)0x3F80, (short)0x3F80, (short)0x3F80, (short)0x3F80};
    f32x4 o[4];
#pragma unroll
    for (int n = 0; n < 4; ++n) o[n] = vzero;
    f32x4 acc_l = vzero;                          // l accumulates on MFMA pipe
    const int ktiles = (qb * 64 + 63) / 128 + 1;
    char* KsB = (char*)Ks; char* VsB = (char*)Vs;

    for (int kt = 0; kt < ktiles; ++kt) {
        const int kbase = kt * 128;
        __syncthreads();
        // stage K tile: wave w rows [w*32,+32), chunk-swizzled source
#pragma unroll
        for (int j = 0; j < 4; ++j) {
            int r0 = w * 32 + j * 8;
            int r = r0 + (lane >> 3);
            int cs = (lane & 7) ^ (r & 7);
            gload16(Kg + ((size_t)bh * Tt + kbase + r) * DHh + cs * 8, KsB + r0 * 128);
        }
        // stage V tile: LINEAR 4KB per wave from pre-permuted VTg
        {
            const u16* vsrc = VTg + (((size_t)bh * 16 + kt) * 8192) + w * 2048 + lane * 8;
#pragma unroll
            for (int j = 0; j < 4; ++j)
                gload16(vsrc + j * 512, VsB + w * 4096 + j * 1024);
        }
        __syncthreads();
        // S^T = K Q^T + mask-bias (C-operand): lane q = lr, k = 16*nf + 4*lg + i
        f32x4 s[8];
        const float* bb = dmb + (size_t)b * Tt + kbase + 4 * lg;
#pragma unroll
        for (int nf = 0; nf < 8; ++nf) {
            int r = nf * 16 + lr;
            short8 k0v = *(const short8*)(KsB + r * 128 + (((0 + lg) ^ (r & 7)) << 4));
            short8 k1v = *(const short8*)(KsB + r * 128 + (((4 + lg) ^ (r & 7)) << 4));
            f32x4 cin = *(const f32x4*)(bb + nf * 16);
            f32x4 t0 = __builtin_amdgcn_mfma_f32_16x16x32_bf16(k0v, qf0, cin, 0, 0, 0);
            s[nf] = __builtin_amdgcn_mfma_f32_16x16x32_bf16(k1v, qf1, t0, 0, 0, 0);
        }
        // causal cut, diagonal tiles only (wave-uniform branch)
        if (kbase + 127 > q0) {
#pragma unroll
            for (int nf = 0; nf < 8; ++nf) {
                int tk = kbase + 16 * nf + 4 * lg;
#pragma unroll
                for (int i = 0; i < 4; ++i)
                    if (tk + i > qrow) s[nf][i] -= 15000.f;
            }
        }
        // PV: pf lane-local (pi-permuted keys), V read matches pi via VTg layout
#pragma unroll
        for (int ks = 0; ks < 4; ++ks) {
            union { uint4 u; short8 sv; } pf;
            pf.u.x = pk2bf(exp2f(s[2 * ks][0]), exp2f(s[2 * ks][1]));
            pf.u.y = pk2bf(exp2f(s[2 * ks][2]), exp2f(s[2 * ks][3]));
            pf.u.z = pk2bf(exp2f(s[2 * ks + 1][0]), exp2f(s[2 * ks + 1][1]));
            pf.u.w = pk2bf(exp2f(s[2 * ks + 1][2]), exp2f(s[2 * ks + 1][3]));
            acc_l = __builtin_amdgcn_mfma_f32_16x16x32_bf16(ones8, pf.sv, acc_l, 0, 0, 0);
#pragma unroll
            for (int n = 0; n < 4; ++n) {
                int rv = n * 16 + lr;
                short8 vf = *(const short8*)(VsB + rv * 256 + ((((ks * 4 + lg)) ^ (rv & 7)) << 4));
                o[n] = __builtin_amdgcn_mfma_f32_16x16x32_bf16(vf, pf.sv, o[n], 0, 0, 0);
            }
        }
    }
    // epilogue: normalize by l = acc_l[0] (same value across D rows), write O
    float l = acc_l[0];
    float inv = l > 0.f ? 1.0f / l : 0.f;
#pragma unroll
    for (int n = 0; n < 4; ++n) {
        uint2 pw;
        pw.x = pk2bf(o[n][0] * inv, o[n][1] * inv);
        pw.y = pk2bf(o[n][2] * inv, o[n][3] * inv);
        *(uint2*)(Og + ((size_t)(b * Tt + qrow)) * Dd + h * DHh + n * 16 + 4 * lg) = pw;
    }
}

// ---------------------------------------------------------------------------
// Output GEMM (measured ~13.5us): 64x128 tiles, grid (8,64)=512 blocks,
// LDS 12KB -> high occupancy. 4 waves (2x2), each 32x64.
// ---------------------------------------------------------------------------
__global__ __launch_bounds__(256) void out_gemm_k(const u16* __restrict__ Og, const u16* __restrict__ wpt,
        const float* __restrict__ bp, const int* __restrict__ dmask, float* __restrict__ out) {
    __shared__ alignas(16) u16 As[64 * 32];    // 4KB
    __shared__ alignas(16) u16 Bs[128 * 32];   // 8KB
    f32x4 acc[2][4];
    const f32x4 vzero = {0.f, 0.f, 0.f, 0.f};
#pragma unroll
    for (int m = 0; m < 2; ++m)
#pragma unroll
        for (int n = 0; n < 4; ++n) acc[m][n] = vzero;
    const int m0 = blockIdx.y * 64, n0 = blockIdx.x * 128;
    const int tid = threadIdx.x, w = tid >> 6, lane = tid & 63, lr = lane & 15, lg = lane >> 4;
    const int wr = w >> 1, wc = w & 1;

    for (int kk = 0; kk < 1024; kk += 32) {
        __syncthreads();
        {
            int row = tid >> 2, c = tid & 3;    // A: 64 rows x 4 chunks
            gload16(Og + (size_t)(m0 + row) * 1024 + kk + c * 8, (char*)As + tid * 16);
#pragma unroll
            for (int j = 0; j < 2; ++j) {
                int idx = tid + j * 256;        // B: 128 rows x 4 chunks
                int rowb = idx >> 2, cb = idx & 3;
                gload16(wpt + (size_t)(n0 + rowb) * 1024 + kk + cb * 8, (char*)Bs + idx * 16);
            }
        }
        __syncthreads();
        short8 af[2], bf[4];
#pragma unroll
        for (int m = 0; m < 2; ++m) {
            int ra = wr * 32 + m * 16 + lr;
            af[m] = *(const short8*)((const char*)As + ra * 64 + lg * 16);
        }
#pragma unroll
        for (int n = 0; n < 4; ++n) {
            int rb = wc * 64 + n * 16 + lr;
            bf[n] = *(const short8*)((const char*)Bs + rb * 64 + lg * 16);
        }
#pragma unroll
        for (int m = 0; m < 2; ++m)
#pragma unroll
            for (int n = 0; n < 4; ++n)
                acc[m][n] = __builtin_amdgcn_mfma_f32_16x16x32_bf16(af[m], bf[n], acc[m][n], 0, 0, 0);
    }
#pragma unroll
    for (int n = 0; n < 4; ++n) {
        int gn = n0 + wc * 64 + n * 16 + lr;
        float bj = bp[gn];
#pragma unroll
        for (int m = 0; m < 2; ++m) {
            int gmb = m0 + wr * 32 + m * 16 + 4 * lg;
#pragma unroll
            for (int i = 0; i < 4; ++i) {
                int gm = gmb + i;
                float dmv = (float)dmask[gm];
                out[(size_t)gm * Dd + gn] = (acc[m][n][i] + bj) * dmv;
            }
        }
    }
}

// ---------------------------------------------------------------------------
// Workspace layout (bytes):
//   [0,8M)    xb  bf16 [4096][1024]   (reused as Og after qkv_gemm)
//   [8M,16M)  wt  bf16 [4][1024][1024] (WqT,WkT,WvT,WpT)
//   [16M,24M) Qg  bf16 [32][2048][64]  (scaled incl log2e)
//   [24M,32M) Kg  bf16 [32][2048][64]
//   [32M,40M) VTg bf16 [32][16][64][128] (V pre-permuted 128-key 16KB tiles)
//   [40M,+16K) dmb f32 [2][2048] additive mask bias
// ---------------------------------------------------------------------------
extern "C" void kernel_launch(void* const* d_in, const int* in_sizes, int n_in,
                              void* d_out, int out_size, void* d_ws, size_t ws_size,
                              hipStream_t stream) {
    const float* x   = (const float*)d_in[0];
    const int*  dmask = (const int*)d_in[1];
    const float* Wq = (const float*)d_in[2];
    const float* bq = (const float*)d_in[3];
    const float* Wk = (const float*)d_in[4];
    const float* bk = (const float*)d_in[5];
    const float* Wv = (const float*)d_in[6];
    const float* bv = (const float*)d_in[7];
    const float* Wp = (const float*)d_in[8];
    const float* bp = (const float*)d_in[9];
    float* out = (float*)d_out;
    char* ws = (char*)d_ws;
    u16* xb  = (u16*)(ws);
    u16* wt  = (u16*)(ws + ((size_t)8 << 20));
    u16* Qg  = (u16*)(ws + ((size_t)16 << 20));
    u16* Kg  = (u16*)(ws + ((size_t)24 << 20));
    u16* VTg = (u16*)(ws + ((size_t)32 << 20));
    float* dmb = (float*)(ws + ((size_t)40 << 20));
    u16* Og  = xb;   // reuse: xb consumed by qkv_gemm before attn writes Og

    prep_k<<<dim3(4096, 2), dim3(256), 0, stream>>>((const float4*)x, (ushort4*)xb,
                                                    (Bb * Tt * Dd) / 4, dmask, dmb,
                                                    Wq, Wk, Wv, Wp, wt);
    qkv_gemm_k<<<dim3(768), dim3(256), 0, stream>>>(xb, wt, bq, bk, bv, Qg, Kg, VTg);
    attn_k<<<dim3(32, 32), dim3(256), 0, stream>>>(Qg, Kg, VTg, dmb, Og);
    out_gemm_k<<<dim3(8, 64), dim3(256), 0, stream>>>(Og, wt + (size_t)3 * Dd * Dd, bp, dmask, out);
}